// Round 7
// baseline (464.442 us; speedup 1.0000x reference)
//
#include <hip/hip_runtime.h>
#include <cstdint>
#include <climits>
#include <cstddef>

#define TK 13
#define MAXG 128

__device__ __forceinline__ float iou_fn(const float4 pb, const float4 gb){
  float pa = (pb.z - pb.x) * (pb.w - pb.y);
  float ga = (gb.z - gb.x) * (gb.w - gb.y);
  float ltx = fmaxf(pb.x, gb.x), lty = fmaxf(pb.y, gb.y);
  float rbx = fminf(pb.z, gb.z), rby = fminf(pb.w, gb.w);
  float w = fmaxf(rbx - ltx, 0.0f), h = fmaxf(rby - lty, 0.0f);
  float inter = w * h;
  float uni = pa + ga - inter;
  return inter / fmaxf(uni, 1e-6f);
}

__device__ __forceinline__ float sigmoid_f(float x){ return 1.0f / (1.0f + expf(-x)); }

// Same expression order as R0-R6 (passed absmax 0) — do not alter.
__device__ __forceinline__ float cost_full(float iou, float s, float dist){
  float sig = sigmoid_f(s);
  float iouc = -logf(iou + 1e-7f) * 3.0f;
  float scale = iou - sig;
  float bce = fmaxf(s, 0.0f) + log1pf(expf(-fabsf(s))) - s * iou;
  float cls = bce * scale * scale;
  float soft = powf(10.0f, dist - 3.0f);
  return cls + iouc + soft;
}

// descending u64 sorted-insert, list[0] largest; sentinel 0
__device__ __forceinline__ void ins13(unsigned long long* a, unsigned long long k){
  if (k <= a[TK-1]) return;
  #pragma unroll
  for (int j = 0; j < TK; ++j){
    if (k > a[j]){ unsigned long long t = a[j]; a[j] = k; k = t; }
  }
}

__device__ __forceinline__ void bfly_max_u64(unsigned long long &v, int &l){
  #pragma unroll
  for (int off = 32; off >= 1; off >>= 1){
    unsigned long long ov = __shfl_xor(v, off);
    int ol = __shfl_xor(l, off);
    if (ov > v){ v = ov; l = ol; }
  }
}

__device__ __forceinline__ unsigned long long wave_max_u64(unsigned long long v){
  #pragma unroll
  for (int off = 32; off >= 1; off >>= 1){
    unsigned long long ov = __shfl_xor(v, off);
    if (ov > v) v = ov;
  }
  return v;
}

// 13th-largest of one key per lane (0 if fewer than 13 nonzero). All lanes get it.
__device__ __forceinline__ unsigned long long red13(unsigned long long k, int lane){
  unsigned long long w = 0;
  for (int r = 0; r < TK; ++r){
    unsigned long long v = k; int l = lane;
    bfly_max_u64(v, l);
    w = v;
    if (lane == l) k = 0;
  }
  return w;
}

// one wave merges 64 sorted desc lists (1/lane) in L[64*TK]; r-th winner on lane r.
__device__ __forceinline__ unsigned long long merge64(const unsigned long long* L, int lane){
  int ptr = 0;
  unsigned long long h = L[lane*TK];
  unsigned long long w = 0;
  for (int r = 0; r < TK; ++r){
    unsigned long long v = h; int l = lane;
    bfly_max_u64(v, l);
    if (lane == r) w = v;
    if (lane == l){ ptr++; h = (ptr < TK) ? L[lane*TK + ptr] : 0ull; }
  }
  return w;
}

// Kernel T: tiled transpose pred_scores[b,p,c] -> scoresT[b,c,p]. C <= 80.
__global__ __launch_bounds__(256) void k_tr(
    const float* __restrict__ in, float* __restrict__ outT, int P, int C)
{
  int b = blockIdx.y;
  int p0 = blockIdx.x * 64;
  __shared__ float t[64 * 81];   // +1 pad breaks the 32-way bank collision
  const float* src = in + ((size_t)b * P + p0) * C;
  int np = P - p0; if (np > 64) np = 64;
  int n = np * C;
  int tot = 64 * C;
  for (int i = threadIdx.x; i < tot; i += 256){
    int pl = i / C, cc = i - pl * C;
    t[pl * 81 + cc] = (i < n) ? src[i] : 0.0f;
  }
  __syncthreads();
  int pl = threadIdx.x & 63;
  int c0 = threadIdx.x >> 6;     // 0..3
  if (p0 + pl < P){
    for (int c = c0; c < C; c += 4)
      outT[((size_t)b * C + c) * P + p0 + pl] = t[pl * 81 + c];
  }
}

// Kernel A: valid bitmask (ballot per wave) + acc init.
__global__ __launch_bounds__(256) void k_valid(
    const float4* __restrict__ priors, const float4* __restrict__ gtb,
    const float* __restrict__ pad, unsigned long long* __restrict__ vmask,
    unsigned int* __restrict__ acc, int P, int G, int nCh)
{
  int b = blockIdx.y;
  int p = blockIdx.x * 256 + threadIdx.x;
  __shared__ float4 sg[MAXG];
  __shared__ float sp[MAXG];
  for (int i = threadIdx.x; i < G; i += 256){ sg[i] = gtb[b*G + i]; sp[i] = pad[b*G + i]; }
  __syncthreads();
  if (p >= P) return;
  float4 pr = priors[p];
  bool v = false;
  #pragma unroll 4
  for (int g = 0; g < G; ++g){
    float4 gb = sg[g];
    bool ig = (pr.x > gb.x) && (pr.y > gb.y) && (gb.z > pr.x) && (gb.w > pr.y);
    v = v || (ig && sp[g] > 0.5f);
  }
  size_t o = (size_t)b * P + p;
  acc[o] = 0u;
  unsigned long long m = __ballot(v);
  if ((threadIdx.x & 63) == 0) vmask[(size_t)b * nCh + (p >> 6)] = m;
}

// Kernel B1: one single-wave block per (b,g,slice). Slice = chunks c≡s (mod S)
// of 64 priors. Register-only wave-uniform prune bounds; scores via transposed
// row (contiguous, prefetched) when useT, else scattered gather fallback.
__global__ __launch_bounds__(64) void k_scan(
    const float4* __restrict__ pred_bboxes, const float* __restrict__ pred_scores,
    const float* __restrict__ scT, int useT,
    const float4* __restrict__ priors, const int* __restrict__ gt_labels,
    const float4* __restrict__ gtbb, const float* __restrict__ pad,
    const unsigned long long* __restrict__ vmask,
    unsigned long long* __restrict__ wsM, unsigned long long* __restrict__ wsC,
    unsigned long long* __restrict__ wsI,
    int P, int G, int C, int S, int nCh)
{
  int bg = blockIdx.x;
  int s  = blockIdx.y;
  if (pad[bg] <= 0.5f) return;
  int b = bg / G;
  int lane = threadIdx.x;
  float4 gb = gtbb[bg];
  int lbl = gt_labels[bg];
  float gcx = (gb.x + gb.z) * 0.5f, gcy = (gb.y + gb.w) * 0.5f;
  size_t bP = (size_t)b * P;
  const unsigned long long* vmb = vmask + (size_t)b * nCh;
  const float* srowT = scT + ((size_t)b * C + lbl) * P;

  __shared__ unsigned long long slist[64 * TK];

  unsigned long long ml[TK], cl[TK];
  float ivl[TK];
  #pragma unroll
  for (int j = 0; j < TK; ++j){ ml[j] = 0ull; cl[j] = 0ull; ivl[j] = -1.0f; }

  float thr = 1e30f;   // dist prune threshold (wave-uniform)
  float mB  = 0.0f;    // metric prune bound (wave-uniform)

  int c = s;
  int p = c * 64 + lane;
  bool inb = p < P;
  float4 pr = make_float4(0,0,0,0), pb = pr; bool vb = false; float spf = 0.0f;
  if (inb){
    pr = priors[p]; pb = pred_bboxes[bP + p]; vb = (vmb[c] >> lane) & 1ull;
    if (useT) spf = srowT[p];
  }
  int it = 0;
  while (c < nCh){
    int cn = c + S;
    int pn = cn * 64 + lane;
    bool inbn = (cn < nCh) && (pn < P);
    float4 prn = make_float4(0,0,0,0), pbn = prn; bool vbn = false; float spfn = 0.0f;
    if (inbn){
      prn = priors[pn]; pbn = pred_bboxes[bP + pn]; vbn = (vmb[cn] >> lane) & 1ull;
      if (useT) spfn = srowT[pn];
    }
    if (inb){
      float iou = iou_fn(pb, gb);
      if (iou > ivl[TK-1]){
        float v = iou;
        #pragma unroll
        for (int j = 0; j < TK; ++j){ if (v > ivl[j]){ float t = ivl[j]; ivl[j] = v; v = t; } }
      }
      bool ig = (pr.x > gb.x) && (pr.y > gb.y) && (gb.z > pr.x) && (gb.w > pr.y);
      float i2 = iou * iou;
      float bnd = (i2 * i2) * i2 * 1.000002f;     // >= sigmoid*powf(iou,6)
      bool need_m = ig && !(bnd < mB);
      float dist = 0.0f; bool need_c = false;
      if (vb){
        float dx = pr.x - gcx, dy = pr.y - gcy;
        dist = sqrtf(dx*dx + dy*dy) / pr.z;
        need_c = !(dist > thr);
      }
      float sc = spf;
      if (!useT && (need_m || need_c)) sc = pred_scores[(bP + p) * C + lbl];
      if (need_m){
        float met = sigmoid_f(sc) * powf(iou, 6.0f);
        ins13(ml, ((unsigned long long)__float_as_uint(met) << 32)
                  | (unsigned)~(unsigned)((p << 1) | 1));
      } else if (!ig){
        ins13(ml, (unsigned long long)(unsigned)~(unsigned)(p << 1));  // metric==0, index tie
      }
      if (!vb || need_c){
        float cst = vb ? cost_full(iou, sc, dist) : 1e8f;
        ins13(cl, ~(((unsigned long long)__float_as_uint(cst) << 32) | (unsigned)p));
      }
    }
    // wave-uniform bound refresh (register-only; sound upper bounds on block 13th-best)
    if (it == 0 || it == 1 || it == 3 || it == 7){
      unsigned long long kb = wave_max_u64(cl[TK-1]);
      if (it == 0){
        unsigned long long k2 = red13(cl[0], lane);
        if (k2 > kb) kb = k2;
      }
      if (kb != 0ull){
        float cb = __uint_as_float((unsigned)((~kb) >> 32));
        float nthr = 3.0f + log10f(cb * 1.00002f + 1e-6f);
        thr = fminf(thr, nthr);
      }
      if (it == 0 || it == 3){
        unsigned long long km = wave_max_u64(ml[TK-1]);
        if (it == 0){
          unsigned long long k2 = red13(ml[0], lane);
          if (k2 > km) km = k2;
        }
        float mb2 = __uint_as_float((unsigned)(km >> 32));
        if (mb2 > mB) mB = mb2;
      }
    }
    c = cn; p = pn; inb = inbn; pr = prn; pb = pbn; vb = vbn; spf = spfn; ++it;
  }

  size_t base = ((size_t)bg * S + s) * TK;
  // metric
  #pragma unroll
  for (int j = 0; j < TK; ++j) slist[lane*TK + j] = ml[j];
  __syncthreads();
  { unsigned long long w = merge64(slist, lane); if (lane < TK) wsM[base + lane] = w; }
  __syncthreads();
  // cost
  #pragma unroll
  for (int j = 0; j < TK; ++j) slist[lane*TK + j] = cl[j];
  __syncthreads();
  { unsigned long long w = merge64(slist, lane); if (lane < TK) wsC[base + lane] = w; }
  __syncthreads();
  // iou (block-unique low bits; rewritten globally unique on write)
  #pragma unroll
  for (int j = 0; j < TK; ++j){
    float v = ivl[j] > 0.0f ? ivl[j] : 0.0f;
    slist[lane*TK + j] = ((unsigned long long)__float_as_uint(v) << 32) | (unsigned)(lane*TK + j + 1);
  }
  __syncthreads();
  { unsigned long long w = merge64(slist, lane);
    if (lane < TK) wsI[base + lane] = (w & 0xFFFFFFFF00000000ull) | (unsigned)(s*TK + lane + 1); }
}

// Kernel B2: one wave per (b,g). Merge S*13 slice winners per criterion (keys
// globally unique, p partitioned across slices); scatter into acc.
__global__ __launch_bounds__(64) void k_merge(
    const unsigned long long* __restrict__ wsM, const unsigned long long* __restrict__ wsC,
    const unsigned long long* __restrict__ wsI, const float* __restrict__ pad,
    unsigned int* __restrict__ acc, int P, int G, int S)
{
  int bg = blockIdx.x;
  if (pad[bg] <= 0.5f) return;
  int b = bg / G;
  int g = bg - b * G;
  int lane = threadIdx.x;
  size_t bP = (size_t)b * P;
  int n = S * TK;
  // metric -> fg marks
  {
    const unsigned long long* base = wsM + (size_t)bg * n;
    unsigned long long k0 = (lane < n) ? base[lane] : 0ull;
    unsigned long long k1 = (lane + 64 < n) ? base[lane + 64] : 0ull;
    for (int r = 0; r < TK; ++r){
      unsigned long long m = k0 > k1 ? k0 : k1; int l = lane;
      bfly_max_u64(m, l);
      if (m == 0ull) break;
      if (lane == 0){
        unsigned ix = ~(unsigned)(m & 0xFFFFFFFFull);
        if (ix & 1u) atomicOr(&acc[bP + (ix >> 1)], 2u);
      }
      if (lane == l){ if (k0 == m) k0 = 0ull; else k1 = 0ull; }
    }
  }
  // iou -> dynamic_k (desc-order sum)
  int kd;
  {
    const unsigned long long* base = wsI + (size_t)bg * n;
    unsigned long long k0 = (lane < n) ? base[lane] : 0ull;
    unsigned long long k1 = (lane + 64 < n) ? base[lane + 64] : 0ull;
    float ksum = 0.0f;
    for (int r = 0; r < TK; ++r){
      unsigned long long m = k0 > k1 ? k0 : k1; int l = lane;
      bfly_max_u64(m, l);
      ksum += __uint_as_float((unsigned)(m >> 32));
      if (lane == l){ if (k0 == m) k0 = 0ull; else k1 = 0ull; }
    }
    kd = (int)ksum; if (kd < 1) kd = 1;
  }
  // cost -> emit first kd selections
  {
    const unsigned long long* base = wsC + (size_t)bg * n;
    unsigned long long k0 = (lane < n) ? base[lane] : 0ull;
    unsigned long long k1 = (lane + 64 < n) ? base[lane + 64] : 0ull;
    for (int r = 0; r < kd; ++r){
      unsigned long long m = k0 > k1 ? k0 : k1; int l = lane;
      bfly_max_u64(m, l);
      if (m == 0ull) break;
      if (lane == 0){
        unsigned p = (unsigned)((~m) & 0xFFFFFFFFull);
        atomicAdd(&acc[bP + p], (1u << 17) | ((unsigned)g << 2));
      }
      if (lane == l){ if (k0 == m) k0 = 0ull; else k1 = 0ull; }
    }
  }
}

// Kernel C: per (b,p) decode acc; multi-match -> dist-pruned argmin-cost; write outputs.
__global__ __launch_bounds__(256) void k_final(
    const float4* __restrict__ pred_bboxes, const float* __restrict__ pred_scores,
    const float4* __restrict__ priors, const int* __restrict__ gt_labels,
    const float4* __restrict__ gtb, const unsigned long long* __restrict__ vmask,
    const unsigned int* __restrict__ acc, float* __restrict__ out,
    int B, int P, int G, int C, int nCh)
{
  int b = blockIdx.y;
  int p = blockIdx.x * 256 + threadIdx.x;
  __shared__ float4 sg[MAXG];
  __shared__ int sl[MAXG];
  __shared__ float2 sc[MAXG];
  for (int i = threadIdx.x; i < G; i += 256){
    float4 gbx = gtb[b*G + i];
    sg[i] = gbx; sl[i] = gt_labels[b*G + i];
    sc[i] = make_float2((gbx.x + gbx.z) * 0.5f, (gbx.y + gbx.w) * 0.5f);
  }
  __syncthreads();
  if (p >= P) return;
  size_t o = (size_t)b * P + p;
  unsigned int w = acc[o];
  int cnt = (int)(w >> 17);
  bool fg = cnt > 0;
  int mg = 0;
  float4 pb = pred_bboxes[o];
  if (cnt == 1){
    mg = (int)((w >> 2) & 0x7FFFu);
  } else if (cnt > 1){
    bool vld = (vmask[(size_t)b * nCh + (p >> 6)] >> (p & 63)) & 1ull;
    if (vld){
      float4 pr = priors[p];
      const float* srow = pred_scores + o * C;
      float bd2 = __builtin_inff(); int gd = 0;
      for (int gg = 0; gg < G; ++gg){
        float dx = pr.x - sc[gg].x, dy = pr.y - sc[gg].y;
        float d2 = dx*dx + dy*dy;
        if (d2 < bd2){ bd2 = d2; gd = gg; }
      }
      float dxs = pr.x - sc[gd].x, dys = pr.y - sc[gd].y;
      float ds0 = sqrtf(dxs*dxs + dys*dys) / pr.z;
      float bestc = cost_full(iou_fn(pb, sg[gd]), srow[sl[gd]], ds0);
      mg = gd;
      for (int gg = 0; gg < G; ++gg){
        float dxx = pr.x - sc[gg].x, dyy = pr.y - sc[gg].y;
        float dd = sqrtf(dxx*dxx + dyy*dyy) / pr.z;
        float lb = exp2f((dd - 3.0f) * 3.321928f) * 0.9999f - 1e-6f; // <= powf(10,dd-3)
        if (lb > bestc) continue;
        float cc = cost_full(iou_fn(pb, sg[gg]), srow[sl[gg]], dd);
        if (cc < bestc || (cc == bestc && gg < mg)){ bestc = cc; mg = gg; }
      }
    } else {
      mg = 0;  // all costs 1e8 -> argmin = 0
    }
  }
  size_t BP = (size_t)B * P;
  out[o] = fg ? (float)sl[mg] : 80.0f;            // assigned_labels
  out[BP + o] = 1.0f;                             // assigned_labels_weights
  float4 ob = fg ? sg[mg] : make_float4(0.f, 0.f, 0.f, 0.f);
  ((float4*)(out + 2*BP))[o] = ob;                // assigned_bboxes
  out[6*BP + o] = fg ? iou_fn(pb, sg[mg]) : 0.0f; // assign_metrics
  out[7*BP + o] = ((w >> 1) & 1u) ? 1.0f : 0.0f;  // fg_mask_pre_prior
}

extern "C" void kernel_launch(void* const* d_in, const int* in_sizes, int n_in,
                              void* d_out, int out_size, void* d_ws, size_t ws_size,
                              hipStream_t stream)
{
  const float4* pred_bboxes = (const float4*)d_in[0];
  const float*  pred_scores = (const float*)d_in[1];
  const float4* priors      = (const float4*)d_in[2];
  const int*    gt_labels   = (const int*)d_in[3];
  const float4* gt_bboxes   = (const float4*)d_in[4];
  const float*  pad         = (const float*)d_in[5];
  int P = in_sizes[2] / 4;                 // 8400
  int B = in_sizes[0] / (P * 4);           // 16
  int C = in_sizes[1] / (B * P);           // 80
  int G = in_sizes[4] / (B * 4);           // 100
  int BG = B * G;
  int nCh = (P + 63) >> 6;                 // 132

  uint8_t* ws = (uint8_t*)d_ws;
  size_t accOff = (size_t)B * nCh * 8;                    // vmask
  size_t fixed  = accOff + (size_t)B * P * 4;             // + acc
  fixed = (fixed + 7) & ~(size_t)7;
  int S = 4;
  while (S > 1 && fixed + 3ull * BG * S * TK * 8 > ws_size) S >>= 1;
  size_t wsEnd = fixed + 3ull * BG * S * TK * 8;
  wsEnd = (wsEnd + 15) & ~(size_t)15;
  size_t scTbytes = (size_t)B * C * P * 4;                // 43 MB
  int useT = (C <= 80) && (wsEnd + scTbytes <= ws_size);

  unsigned long long* vmask = (unsigned long long*)ws;
  unsigned int* acc = (unsigned int*)(ws + accOff);
  unsigned long long* wsM = (unsigned long long*)(ws + fixed);
  unsigned long long* wsC = wsM + (size_t)BG * S * TK;
  unsigned long long* wsI = wsC + (size_t)BG * S * TK;
  float* scT = (float*)(ws + wsEnd);
  float* out = (float*)d_out;

  dim3 gridA((P + 255) / 256, B);
  if (useT) k_tr<<<dim3(nCh, B), 256, 0, stream>>>(pred_scores, scT, P, C);
  k_valid<<<gridA, 256, 0, stream>>>(priors, gt_bboxes, pad, vmask, acc, P, G, nCh);
  k_scan<<<dim3(BG, S), 64, 0, stream>>>(pred_bboxes, pred_scores, scT, useT,
                                         priors, gt_labels, gt_bboxes,
                                         pad, vmask, wsM, wsC, wsI, P, G, C, S, nCh);
  k_merge<<<BG, 64, 0, stream>>>(wsM, wsC, wsI, pad, acc, P, G, S);
  k_final<<<gridA, 256, 0, stream>>>(pred_bboxes, pred_scores, priors, gt_labels, gt_bboxes,
                                     vmask, acc, out, B, P, G, C, nCh);
}

// Round 8
// 368.397 us; speedup vs baseline: 1.2607x; 1.2607x over previous
//
#include <hip/hip_runtime.h>
#include <cstdint>
#include <climits>
#include <cstddef>

#define TK 13
#define MAXG 128
#define CAP 192
#define MCAP 24576

__device__ __forceinline__ float iou_fn(const float4 pb, const float4 gb){
  float pa = (pb.z - pb.x) * (pb.w - pb.y);
  float ga = (gb.z - gb.x) * (gb.w - gb.y);
  float ltx = fmaxf(pb.x, gb.x), lty = fmaxf(pb.y, gb.y);
  float rbx = fminf(pb.z, gb.z), rby = fminf(pb.w, gb.w);
  float w = fmaxf(rbx - ltx, 0.0f), h = fmaxf(rby - lty, 0.0f);
  float inter = w * h;
  float uni = pa + ga - inter;
  return inter / fmaxf(uni, 1e-6f);
}

__device__ __forceinline__ float sigmoid_f(float x){ return 1.0f / (1.0f + expf(-x)); }

// Same expression order as R0-R7 (passed absmax 0) — do not alter.
__device__ __forceinline__ float cost_full(float iou, float s, float dist){
  float sig = sigmoid_f(s);
  float iouc = -logf(iou + 1e-7f) * 3.0f;
  float scale = iou - sig;
  float bce = fmaxf(s, 0.0f) + log1pf(expf(-fabsf(s))) - s * iou;
  float cls = bce * scale * scale;
  float soft = powf(10.0f, dist - 3.0f);
  return cls + iouc + soft;
}

__device__ __forceinline__ void bfly_max_u64(unsigned long long &v, int &l){
  #pragma unroll
  for (int off = 32; off >= 1; off >>= 1){
    unsigned long long ov = __shfl_xor(v, off);
    int ol = __shfl_xor(l, off);
    if (ov > v){ v = ov; l = ol; }
  }
}

// find 13th-largest of cnt (>=13) entries in buf; compact top-13 to buf[0..12];
// return T = 13th key. Single-wave; keys unique/nonzero.
__device__ __forceinline__ unsigned long long squeeze13(unsigned long long* buf, int& cnt, int lane){
  unsigned long long e0 = (lane < cnt) ? buf[lane] : 0ull;
  unsigned long long e1 = (lane + 64 < cnt) ? buf[lane + 64] : 0ull;
  unsigned long long e2 = (lane + 128 < cnt) ? buf[lane + 128] : 0ull;
  if (e0 < e2){ unsigned long long t = e0; e0 = e2; e2 = t; }
  if (e0 < e1){ unsigned long long t = e0; e0 = e1; e1 = t; }
  if (e1 < e2){ unsigned long long t = e1; e1 = e2; e2 = t; }
  unsigned long long T = 0;
  for (int r = 0; r < TK; ++r){
    unsigned long long m = e0; int l = lane;
    bfly_max_u64(m, l);
    if (lane == 0) buf[r] = m;
    T = m;
    if (lane == l){ e0 = e1; e1 = e2; e2 = 0ull; }
  }
  cnt = TK;
  return T;
}

// Kernel T: tiled transpose pred_scores[b,p,c] -> scoresT[b,c,p].
__global__ __launch_bounds__(256) void k_tr(
    const float* __restrict__ in, float* __restrict__ outT, int P, int C)
{
  int b = blockIdx.y;
  int p0 = blockIdx.x * 64;
  __shared__ float t[64 * 81];
  const float* src = in + ((size_t)b * P + p0) * C;
  int np = P - p0; if (np > 64) np = 64;
  int n = np * C;
  int tot = 64 * C;
  for (int i = threadIdx.x; i < tot; i += 256){
    int pl = i / C, cc = i - pl * C;
    t[pl * 81 + cc] = (i < n) ? src[i] : 0.0f;
  }
  __syncthreads();
  int pl = threadIdx.x & 63;
  int c0 = threadIdx.x >> 6;
  if (p0 + pl < P){
    for (int c = c0; c < C; c += 4)
      outT[((size_t)b * C + c) * P + p0 + pl] = t[pl * 81 + c];
  }
}

// Kernel A: valid bitmask + acc init + multi-counter zero.
__global__ __launch_bounds__(256) void k_valid(
    const float4* __restrict__ priors, const float4* __restrict__ gtb,
    const float* __restrict__ pad, unsigned long long* __restrict__ vmask,
    unsigned int* __restrict__ acc, unsigned int* __restrict__ mcnt,
    int P, int G, int nCh)
{
  int b = blockIdx.y;
  int p = blockIdx.x * 256 + threadIdx.x;
  if (b == 0 && p == 0) *mcnt = 0u;
  __shared__ float4 sg[MAXG];
  __shared__ float sp[MAXG];
  for (int i = threadIdx.x; i < G; i += 256){ sg[i] = gtb[b*G + i]; sp[i] = pad[b*G + i]; }
  __syncthreads();
  if (p >= P) return;
  float4 pr = priors[p];
  bool v = false;
  #pragma unroll 4
  for (int g = 0; g < G; ++g){
    float4 gb = sg[g];
    bool ig = (pr.x > gb.x) && (pr.y > gb.y) && (gb.z > pr.x) && (gb.w > pr.y);
    v = v || (ig && sp[g] > 0.5f);
  }
  size_t o = (size_t)b * P + p;
  acc[o] = 0u;
  unsigned long long m = __ballot(v);
  if ((threadIdx.x & 63) == 0) vmask[(size_t)b * nCh + (p >> 6)] = m;
}

// Kernel B: one wave per (b,g). Candidate-buffer scan with wave-uniform
// register thresholds; in-block exact top-13 extraction + scatter.
__global__ __launch_bounds__(64) void k_scan(
    const float4* __restrict__ pred_bboxes, const float* __restrict__ pred_scores,
    const float* __restrict__ scT, int useT,
    const float4* __restrict__ priors, const int* __restrict__ gt_labels,
    const float4* __restrict__ gtbb, const float* __restrict__ pad,
    const unsigned long long* __restrict__ vmask,
    unsigned int* __restrict__ acc, unsigned int* __restrict__ mcnt,
    unsigned int* __restrict__ mlist,
    int P, int G, int C, int nCh)
{
  int bg = blockIdx.x;
  if (pad[bg] <= 0.5f) return;
  int b = bg / G;
  int g = bg - b * G;
  int lane = threadIdx.x;
  float4 gb = gtbb[bg];
  int lbl = gt_labels[bg];
  float gcx = (gb.x + gb.z) * 0.5f, gcy = (gb.y + gb.w) * 0.5f;
  size_t bP = (size_t)b * P;
  const unsigned long long* vmb = vmask + (size_t)b * nCh;
  const float* srowT = scT + ((size_t)b * C + lbl) * P;

  __shared__ unsigned long long bufM[CAP];
  __shared__ unsigned long long bufC[CAP];
  __shared__ unsigned long long bufI[CAP];

  int cntM = 0, cntC = 0, cntI = 0;                    // wave-uniform
  unsigned long long Tm = 0ull, Tc = 0ull;
  unsigned long long Ti = 0x00000000FFFFFFFFull;       // prune iou==0 from the start
  float thr = 1e30f, mB = 0.0f;
  unsigned long long laneLT = (lane == 63) ? 0xFFFFFFFFFFFFFFFFull >> 1
                                           : ((1ull << lane) - 1);
  // (1ull<<63)-1 is fine too; explicit to avoid UB worries
  laneLT = (1ull << lane) - 1ull;

  int p = lane;
  bool inb = p < P;
  float4 pr = make_float4(0,0,0,0), pb = pr; bool vb = false; float spf = 0.0f;
  if (inb){
    pr = priors[p]; pb = pred_bboxes[bP + p]; vb = (vmb[0] >> lane) & 1ull;
    if (useT) spf = srowT[p];
  }
  for (int c = 0; c < nCh; ++c){
    // prefetch next chunk
    int pn = (c + 1) * 64 + lane;
    bool inbn = (c + 1 < nCh) && (pn < P);
    float4 prn = make_float4(0,0,0,0), pbn = prn; bool vbn = false; float spfn = 0.0f;
    if (inbn){
      prn = priors[pn]; pbn = pred_bboxes[bP + pn]; vbn = (vmb[c+1] >> (pn & 63)) & 1ull;
      if (useT) spfn = srowT[pn];
    }
    // ---- compute candidates ----
    float iou = iou_fn(pb, gb);
    bool ig = inb && (pr.x > gb.x) && (pr.y > gb.y) && (gb.z > pr.x) && (gb.w > pr.y);
    unsigned long long keyI = ((unsigned long long)__float_as_uint(iou) << 32) | (unsigned)p;
    bool candI = inb && (keyI > Ti);
    float i2 = iou * iou;
    float bnd = (i2 * i2) * i2 * 1.000002f;            // >= sigmoid*powf(iou,6)
    bool needm = ig && !(bnd < mB);
    float dist = 0.0f; bool needc = false;
    if (vb){
      float dx = pr.x - gcx, dy = pr.y - gcy;
      dist = sqrtf(dx*dx + dy*dy) / pr.z;
      needc = !(dist > thr);
    }
    float sc = spf;
    if (!useT && (needm || needc)) sc = pred_scores[(bP + p) * C + lbl];
    unsigned long long keyM = 0; bool candM = false;
    if (__ballot(needm)){
      float met = sigmoid_f(sc) * powf(iou, 6.0f);
      if (needm){
        keyM = ((unsigned long long)__float_as_uint(met) << 32)
             | (unsigned)~(unsigned)((p << 1) | 1);
        candM = keyM > Tm;
      }
    }
    if (inb && !ig){
      keyM = (unsigned long long)(unsigned)~(unsigned)(p << 1);  // metric==0, index tie
      candM = keyM > Tm;
    }
    unsigned long long keyC = 0; bool candC = false;
    if (inb && !vb){
      keyC = ~(((unsigned long long)__float_as_uint(1e8f) << 32) | (unsigned)p);
      candC = keyC > Tc;
    }
    if (__ballot(needc)){
      float cst = cost_full(iou, sc, dist);
      if (needc){
        keyC = ~(((unsigned long long)__float_as_uint(cst) << 32) | (unsigned)p);
        candC = keyC > Tc;
      }
    }
    // ---- pushes (squeeze-on-full; re-filter after squeeze) ----
    if (cntI > CAP - 64){ Ti = squeeze13(bufI, cntI, lane); candI = candI && (keyI > Ti); }
    { unsigned long long mk = __ballot(candI);
      if (mk){ int off = cntI + __popcll(mk & laneLT); if (candI) bufI[off] = keyI; cntI += __popcll(mk); } }
    if (cntM > CAP - 64){
      Tm = squeeze13(bufM, cntM, lane); candM = candM && (keyM > Tm);
      mB = __uint_as_float((unsigned)(Tm >> 32));
    }
    { unsigned long long mk = __ballot(candM);
      if (mk){ int off = cntM + __popcll(mk & laneLT); if (candM) bufM[off] = keyM; cntM += __popcll(mk); } }
    if (cntC > CAP - 64){
      Tc = squeeze13(bufC, cntC, lane); candC = candC && (keyC > Tc);
      unsigned cbits = (unsigned)((~Tc) >> 32);
      thr = 3.0f + log10f(__uint_as_float(cbits) * 1.00002f + 1e-6f);
    }
    { unsigned long long mk = __ballot(candC);
      if (mk){ int off = cntC + __popcll(mk & laneLT); if (candC) bufC[off] = keyC; cntC += __popcll(mk); } }

    p = pn; inb = inbn; pr = prn; pb = pbn; vb = vbn; spf = spfn;
  }

  // ---- extraction: iou -> kd ----
  int kd;
  {
    unsigned long long e0 = (lane < cntI) ? bufI[lane] : 0ull;
    unsigned long long e1 = (lane + 64 < cntI) ? bufI[lane + 64] : 0ull;
    unsigned long long e2 = (lane + 128 < cntI) ? bufI[lane + 128] : 0ull;
    if (e0 < e2){ unsigned long long t = e0; e0 = e2; e2 = t; }
    if (e0 < e1){ unsigned long long t = e0; e0 = e1; e1 = t; }
    if (e1 < e2){ unsigned long long t = e1; e1 = e2; e2 = t; }
    float ksum = 0.0f;
    for (int r = 0; r < TK; ++r){
      unsigned long long m = e0; int l = lane;
      bfly_max_u64(m, l);
      ksum += __uint_as_float((unsigned)(m >> 32));   // desc-order sum, fp-exact
      if (lane == l){ e0 = e1; e1 = e2; e2 = 0ull; }
    }
    kd = (int)ksum; if (kd < 1) kd = 1;
  }
  // ---- extraction: metric -> fg marks ----
  {
    unsigned long long e0 = (lane < cntM) ? bufM[lane] : 0ull;
    unsigned long long e1 = (lane + 64 < cntM) ? bufM[lane + 64] : 0ull;
    unsigned long long e2 = (lane + 128 < cntM) ? bufM[lane + 128] : 0ull;
    if (e0 < e2){ unsigned long long t = e0; e0 = e2; e2 = t; }
    if (e0 < e1){ unsigned long long t = e0; e0 = e1; e1 = t; }
    if (e1 < e2){ unsigned long long t = e1; e1 = e2; e2 = t; }
    for (int r = 0; r < TK; ++r){
      unsigned long long m = e0; int l = lane;
      bfly_max_u64(m, l);
      if (lane == 0 && m != 0ull){
        unsigned ix = ~(unsigned)(m & 0xFFFFFFFFull);
        if (ix & 1u) atomicOr(&acc[bP + (ix >> 1)], 2u);
      }
      if (lane == l){ e0 = e1; e1 = e2; e2 = 0ull; }
    }
  }
  // ---- extraction: cost -> first kd selections; detect multi on transition ----
  {
    unsigned long long e0 = (lane < cntC) ? bufC[lane] : 0ull;
    unsigned long long e1 = (lane + 64 < cntC) ? bufC[lane + 64] : 0ull;
    unsigned long long e2 = (lane + 128 < cntC) ? bufC[lane + 128] : 0ull;
    if (e0 < e2){ unsigned long long t = e0; e0 = e2; e2 = t; }
    if (e0 < e1){ unsigned long long t = e0; e0 = e1; e1 = t; }
    if (e1 < e2){ unsigned long long t = e1; e1 = e2; e2 = t; }
    for (int r = 0; r < kd; ++r){
      unsigned long long m = e0; int l = lane;
      bfly_max_u64(m, l);
      if (lane == 0 && m != 0ull){
        unsigned pp = (unsigned)((~m) & 0xFFFFFFFFull);
        unsigned old = atomicAdd(&acc[bP + pp], (1u << 17) | ((unsigned)g << 2));
        if ((old >> 17) == 1u){
          unsigned mi = atomicAdd(mcnt, 1u);
          if (mi < MCAP) mlist[mi] = (unsigned)(bP + pp);
        }
      }
      if (lane == l){ e0 = e1; e1 = e2; e2 = 0ull; }
    }
  }
}

// Kernel C: uniform decode; multi priors get a placeholder (k_multi overwrites).
__global__ __launch_bounds__(256) void k_final(
    const float4* __restrict__ pred_bboxes, const int* __restrict__ gt_labels,
    const float4* __restrict__ gtb, const unsigned int* __restrict__ acc,
    float* __restrict__ out, int B, int P, int G)
{
  int b = blockIdx.y;
  int p = blockIdx.x * 256 + threadIdx.x;
  __shared__ float4 sg[MAXG];
  __shared__ int sl[MAXG];
  for (int i = threadIdx.x; i < G; i += 256){
    sg[i] = gtb[b*G + i]; sl[i] = gt_labels[b*G + i];
  }
  __syncthreads();
  if (p >= P) return;
  size_t o = (size_t)b * P + p;
  unsigned int w = acc[o];
  int cnt = (int)(w >> 17);
  bool fg = cnt > 0;
  int mg = (cnt == 1) ? (int)((w >> 2) & 0x7FFFu) : 0;  // cnt>1 -> placeholder
  float4 pb = pred_bboxes[o];
  size_t BP = (size_t)B * P;
  out[o] = fg ? (float)sl[mg] : 80.0f;
  out[BP + o] = 1.0f;
  float4 ob = fg ? sg[mg] : make_float4(0.f, 0.f, 0.f, 0.f);
  ((float4*)(out + 2*BP))[o] = ob;
  out[6*BP + o] = fg ? iou_fn(pb, sg[mg]) : 0.0f;
  out[7*BP + o] = ((w >> 1) & 1u) ? 1.0f : 0.0f;
}

// Kernel D: one wave per multi-matched prior; exact argmin cost over all g.
__global__ __launch_bounds__(256) void k_multi(
    const float4* __restrict__ pred_bboxes, const float* __restrict__ pred_scores,
    const float4* __restrict__ priors, const int* __restrict__ gt_labels,
    const float4* __restrict__ gtb, const unsigned long long* __restrict__ vmask,
    const unsigned int* __restrict__ mcnt, const unsigned int* __restrict__ mlist,
    float* __restrict__ out, int B, int P, int G, int C, int nCh)
{
  unsigned n = *mcnt; if (n > MCAP) n = MCAP;
  int lane = threadIdx.x & 63;
  int wid = (blockIdx.x * (blockDim.x >> 6)) + (threadIdx.x >> 6);
  int nw = gridDim.x * (blockDim.x >> 6);
  size_t BP = (size_t)B * P;
  for (unsigned i = wid; i < n; i += nw){
    unsigned o = mlist[i];
    int b = o / P;
    int p = o - b * P;
    float4 pb = pred_bboxes[o];
    bool vld = (vmask[(size_t)b * nCh + (p >> 6)] >> (p & 63)) & 1ull;
    int mg = 0;
    if (vld){
      float4 pr = priors[p];
      const float* srow = pred_scores + (size_t)o * C;
      unsigned long long best = 0xFFFFFFFFFFFFFFFFull;
      for (int g0 = lane; g0 < G; g0 += 64){
        float4 gbx = gtb[b*G + g0];
        float iou = iou_fn(pb, gbx);
        float s = srow[gt_labels[b*G + g0]];
        float gcx = (gbx.x + gbx.z) * 0.5f, gcy = (gbx.y + gbx.w) * 0.5f;
        float dx = pr.x - gcx, dy = pr.y - gcy;
        float dist = sqrtf(dx*dx + dy*dy) / pr.z;
        float cc = cost_full(iou, s, dist);   // > 0 always (soft >= 1e-3)
        unsigned long long k = ((unsigned long long)__float_as_uint(cc) << 32) | (unsigned)g0;
        if (k < best) best = k;
      }
      #pragma unroll
      for (int off = 32; off >= 1; off >>= 1){
        unsigned long long ov = __shfl_xor(best, off);
        if (ov < best) best = ov;
      }
      mg = (int)(best & 0xFFFFFFFFull);
    }
    if (lane == 0){
      float4 gbx = gtb[b*G + mg];
      out[o] = (float)gt_labels[b*G + mg];
      ((float4*)(out + 2*BP))[o] = gbx;
      out[6*BP + o] = iou_fn(pb, gbx);
    }
  }
}

extern "C" void kernel_launch(void* const* d_in, const int* in_sizes, int n_in,
                              void* d_out, int out_size, void* d_ws, size_t ws_size,
                              hipStream_t stream)
{
  const float4* pred_bboxes = (const float4*)d_in[0];
  const float*  pred_scores = (const float*)d_in[1];
  const float4* priors      = (const float4*)d_in[2];
  const int*    gt_labels   = (const int*)d_in[3];
  const float4* gt_bboxes   = (const float4*)d_in[4];
  const float*  pad         = (const float*)d_in[5];
  int P = in_sizes[2] / 4;                 // 8400
  int B = in_sizes[0] / (P * 4);           // 16
  int C = in_sizes[1] / (B * P);           // 80
  int G = in_sizes[4] / (B * 4);           // 100
  int BG = B * G;
  int nCh = (P + 63) >> 6;                 // 132

  uint8_t* ws = (uint8_t*)d_ws;
  size_t accOff  = (size_t)B * nCh * 8;                 // vmask
  size_t mcntOff = accOff + (size_t)B * P * 4;          // acc
  mcntOff = (mcntOff + 15) & ~(size_t)15;
  size_t mlistOff = mcntOff + 16;
  size_t scTOff = mlistOff + (size_t)MCAP * 4;
  scTOff = (scTOff + 15) & ~(size_t)15;
  size_t scTbytes = (size_t)B * C * P * 4;              // ~43 MB
  int useT = (scTOff + scTbytes <= ws_size);

  unsigned long long* vmask = (unsigned long long*)ws;
  unsigned int* acc   = (unsigned int*)(ws + accOff);
  unsigned int* mcnt  = (unsigned int*)(ws + mcntOff);
  unsigned int* mlist = (unsigned int*)(ws + mlistOff);
  float* scT = (float*)(ws + scTOff);
  float* out = (float*)d_out;

  dim3 gridA((P + 255) / 256, B);
  if (useT) k_tr<<<dim3(nCh, B), 256, 0, stream>>>(pred_scores, scT, P, C);
  k_valid<<<gridA, 256, 0, stream>>>(priors, gt_bboxes, pad, vmask, acc, mcnt, P, G, nCh);
  k_scan<<<BG, 64, 0, stream>>>(pred_bboxes, pred_scores, scT, useT,
                                priors, gt_labels, gt_bboxes, pad, vmask,
                                acc, mcnt, mlist, P, G, C, nCh);
  k_final<<<gridA, 256, 0, stream>>>(pred_bboxes, gt_labels, gt_bboxes, acc, out, B, P, G);
  k_multi<<<64, 256, 0, stream>>>(pred_bboxes, pred_scores, priors, gt_labels, gt_bboxes,
                                  vmask, mcnt, mlist, out, B, P, G, C, nCh);
}

// Round 9
// 319.988 us; speedup vs baseline: 1.4514x; 1.1513x over previous
//
#include <hip/hip_runtime.h>
#include <cstdint>
#include <climits>
#include <cstddef>

#define TK 13
#define MAXG 128
#define CAP 192
#define NW 4
#define MCAP 24576

__device__ __forceinline__ float iou_fn(const float4 pb, const float4 gb){
  float pa = (pb.z - pb.x) * (pb.w - pb.y);
  float ga = (gb.z - gb.x) * (gb.w - gb.y);
  float ltx = fmaxf(pb.x, gb.x), lty = fmaxf(pb.y, gb.y);
  float rbx = fminf(pb.z, gb.z), rby = fminf(pb.w, gb.w);
  float w = fmaxf(rbx - ltx, 0.0f), h = fmaxf(rby - lty, 0.0f);
  float inter = w * h;
  float uni = pa + ga - inter;
  return inter / fmaxf(uni, 1e-6f);
}

__device__ __forceinline__ float sigmoid_f(float x){ return 1.0f / (1.0f + expf(-x)); }

// Same expression order as R0-R8 (passed absmax 0) — do not alter.
__device__ __forceinline__ float cost_full(float iou, float s, float dist){
  float sig = sigmoid_f(s);
  float iouc = -logf(iou + 1e-7f) * 3.0f;
  float scale = iou - sig;
  float bce = fmaxf(s, 0.0f) + log1pf(expf(-fabsf(s))) - s * iou;
  float cls = bce * scale * scale;
  float soft = powf(10.0f, dist - 3.0f);
  return cls + iouc + soft;
}

__device__ __forceinline__ void bfly_max_u64(unsigned long long &v, int &l){
  #pragma unroll
  for (int off = 32; off >= 1; off >>= 1){
    unsigned long long ov = __shfl_xor(v, off);
    int ol = __shfl_xor(l, off);
    if (ov > v){ v = ov; l = ol; }
  }
}

// wave-level: find 13th-largest of cnt entries in buf; compact top-13 to
// buf[0..12]; return 13th key (0 if fewer than 13 nonzero). Keys unique.
__device__ __forceinline__ unsigned long long squeeze13(unsigned long long* buf, int& cnt, int lane){
  unsigned long long e0 = (lane < cnt) ? buf[lane] : 0ull;
  unsigned long long e1 = (lane + 64 < cnt) ? buf[lane + 64] : 0ull;
  unsigned long long e2 = (lane + 128 < cnt) ? buf[lane + 128] : 0ull;
  if (e0 < e2){ unsigned long long t = e0; e0 = e2; e2 = t; }
  if (e0 < e1){ unsigned long long t = e0; e0 = e1; e1 = t; }
  if (e1 < e2){ unsigned long long t = e1; e1 = e2; e2 = t; }
  unsigned long long T = 0;
  for (int r = 0; r < TK; ++r){
    unsigned long long m = e0; int l = lane;
    bfly_max_u64(m, l);
    if (lane == 0) buf[r] = m;
    T = m;
    if (lane == l){ e0 = e1; e1 = e2; e2 = 0ull; }
  }
  cnt = TK;
  return T;
}

// Kernel T: tiled transpose pred_scores[b,p,c] -> scoresT[b,c,p].
__global__ __launch_bounds__(256) void k_tr(
    const float* __restrict__ in, float* __restrict__ outT, int P, int C)
{
  int b = blockIdx.y;
  int p0 = blockIdx.x * 64;
  __shared__ float t[64 * 81];
  const float* src = in + ((size_t)b * P + p0) * C;
  int np = P - p0; if (np > 64) np = 64;
  int n = np * C;
  int tot = 64 * C;
  for (int i = threadIdx.x; i < tot; i += 256){
    int pl = i / C, cc = i - pl * C;
    t[pl * 81 + cc] = (i < n) ? src[i] : 0.0f;
  }
  __syncthreads();
  int pl = threadIdx.x & 63;
  int c0 = threadIdx.x >> 6;
  if (p0 + pl < P){
    for (int c = c0; c < C; c += 4)
      outT[((size_t)b * C + c) * P + p0 + pl] = t[pl * 81 + c];
  }
}

// Kernel A: valid bitmask + acc init + multi-counter zero.
__global__ __launch_bounds__(256) void k_valid(
    const float4* __restrict__ priors, const float4* __restrict__ gtb,
    const float* __restrict__ pad, unsigned long long* __restrict__ vmask,
    unsigned int* __restrict__ acc, unsigned int* __restrict__ mcnt,
    int P, int G, int nCh)
{
  int b = blockIdx.y;
  int p = blockIdx.x * 256 + threadIdx.x;
  if (b == 0 && p == 0) *mcnt = 0u;
  __shared__ float4 sg[MAXG];
  __shared__ float sp[MAXG];
  for (int i = threadIdx.x; i < G; i += 256){ sg[i] = gtb[b*G + i]; sp[i] = pad[b*G + i]; }
  __syncthreads();
  if (p >= P) return;
  float4 pr = priors[p];
  bool v = false;
  #pragma unroll 4
  for (int g = 0; g < G; ++g){
    float4 gb = sg[g];
    bool ig = (pr.x > gb.x) && (pr.y > gb.y) && (gb.z > pr.x) && (gb.w > pr.y);
    v = v || (ig && sp[g] > 0.5f);
  }
  size_t o = (size_t)b * P + p;
  acc[o] = 0u;
  unsigned long long m = __ballot(v);
  if ((threadIdx.x & 63) == 0) vmask[(size_t)b * nCh + (p >> 6)] = m;
}

// Kernel B: one 4-wave block per (b,g). Each wave scans interleaved chunks with
// its own candidate buffers + register thresholds; shared LDS threshold words
// updated only at squeezes; in-block global top-13 extraction + scatter.
__global__ __launch_bounds__(256) void k_scan(
    const float4* __restrict__ pred_bboxes, const float* __restrict__ pred_scores,
    const float* __restrict__ scT, int useT,
    const float4* __restrict__ priors, const int* __restrict__ gt_labels,
    const float4* __restrict__ gtbb, const float* __restrict__ pad,
    const unsigned long long* __restrict__ vmask,
    unsigned int* __restrict__ acc, unsigned int* __restrict__ mcnt,
    unsigned int* __restrict__ mlist,
    int P, int G, int C, int nCh)
{
  int bg = blockIdx.x;
  if (pad[bg] <= 0.5f) return;
  int b = bg / G;
  int g = bg - b * G;
  int tid = threadIdx.x;
  int lane = tid & 63;
  int wv = tid >> 6;
  float4 gb = gtbb[bg];
  int lbl = gt_labels[bg];
  float gcx = (gb.x + gb.z) * 0.5f, gcy = (gb.y + gb.w) * 0.5f;
  size_t bP = (size_t)b * P;
  const unsigned long long* vmb = vmask + (size_t)b * nCh;
  const float* srowT = scT + ((size_t)b * C + lbl) * P;

  __shared__ unsigned long long bufM[NW*CAP], bufC[NW*CAP], bufI[NW*CAP];
  __shared__ unsigned int shwC, shwM, shwI;   // value-bits-only shared bounds
  if (tid == 0){ shwC = 0xFFFFFFFFu; shwM = 0u; shwI = 0u; }
  __syncthreads();
  unsigned long long* bM = bufM + wv*CAP;
  unsigned long long* bC = bufC + wv*CAP;
  unsigned long long* bI = bufI + wv*CAP;

  int cntM = 0, cntC = 0, cntI = 0;                 // wave-uniform
  unsigned long long Tm = 0ull, Tc = 0ull;
  unsigned long long Ti = 0x00000000FFFFFFFFull;    // prune iou==0 from the start
  unsigned cbits = 0xFFFFFFFFu, mBbits = 0u, iBb = 0u;
  float thr = 1e30f, mB = 0.0f;
  unsigned long long laneLT = (1ull << lane) - 1ull;

  int p = wv * 64 + lane;
  bool inb = p < P;
  float4 pr = make_float4(0,0,0,0), pb = pr; bool vb = false; float spf = 0.0f;
  if (inb){
    pr = priors[p]; pb = pred_bboxes[bP + p]; vb = (vmb[wv] >> lane) & 1ull;
    if (useT) spf = srowT[p];
  }
  for (int c = wv; c < nCh; c += NW){
    // prefetch next chunk for this wave
    int cn = c + NW;
    int pn = cn * 64 + lane;
    bool inbn = (cn < nCh) && (pn < P);
    float4 prn = make_float4(0,0,0,0), pbn = prn; bool vbn = false; float spfn = 0.0f;
    if (inbn){
      prn = priors[pn]; pbn = pred_bboxes[bP + pn]; vbn = (vmb[cn] >> (pn & 63)) & 1ull;
      if (useT) spfn = srowT[pn];
    }
    // refresh shared bounds (broadcast LDS reads; recompute thr only on change)
    { unsigned sC = shwC; if (sC < cbits){ cbits = sC;
        thr = 3.0f + log10f(__uint_as_float(cbits) * 1.00002f + 1e-6f); } }
    { unsigned sM = shwM; if (sM > mBbits){ mBbits = sM; mB = __uint_as_float(sM); } }
    { unsigned sI = shwI; if (sI > iBb) iBb = sI; }
    // ---- compute candidates ----
    float iou = iou_fn(pb, gb);
    bool ig = inb && (pr.x > gb.x) && (pr.y > gb.y) && (gb.z > pr.x) && (gb.w > pr.y);
    unsigned long long keyI = ((unsigned long long)__float_as_uint(iou) << 32) | (unsigned)p;
    bool candI = inb && (keyI > Ti) && !((unsigned)(keyI >> 32) < iBb);
    float i2 = iou * iou;
    float bnd = (i2 * i2) * i2 * 1.000002f;          // >= sigmoid*powf(iou,6)
    bool needm = ig && !(bnd < mB);
    float dist = 0.0f; bool needc = false;
    if (vb){
      float dx = pr.x - gcx, dy = pr.y - gcy;
      dist = sqrtf(dx*dx + dy*dy) / pr.z;
      needc = !(dist > thr);
    }
    float sc = spf;
    if (!useT && (needm || needc)) sc = pred_scores[(bP + p) * C + lbl];
    unsigned long long keyM = 0; bool candM = false;
    if (__ballot(needm)){
      float met = sigmoid_f(sc) * powf(iou, 6.0f);
      if (needm)
        keyM = ((unsigned long long)__float_as_uint(met) << 32)
             | (unsigned)~(unsigned)((p << 1) | 1);
    }
    if (inb && !ig)
      keyM = (unsigned long long)(unsigned)~(unsigned)(p << 1);   // metric==0, index tie
    candM = (keyM > Tm) && !((unsigned)(keyM >> 32) < mBbits);
    unsigned long long keyC = 0;
    if (inb && !vb)
      keyC = ~(((unsigned long long)__float_as_uint(1e8f) << 32) | (unsigned)p);
    if (__ballot(needc)){
      float cst = cost_full(iou, sc, dist);
      if (needc)
        keyC = ~(((unsigned long long)__float_as_uint(cst) << 32) | (unsigned)p);
    }
    bool candC = (keyC != 0ull) && (keyC > Tc) && !((unsigned)((~keyC) >> 32) > cbits);
    // ---- pushes (squeeze-on-full; update shared bounds at squeeze only) ----
    if (cntI > CAP - 64){
      Ti = squeeze13(bI, cntI, lane);
      unsigned ib = (unsigned)(Ti >> 32);
      if (ib > iBb) iBb = ib;
      if (lane == 0 && ib) atomicMax(&shwI, ib);
      candI = candI && (keyI > Ti) && !((unsigned)(keyI >> 32) < iBb);
    }
    { unsigned long long mk = __ballot(candI);
      if (mk){ int off = cntI + __popcll(mk & laneLT); if (candI) bI[off] = keyI; cntI += __popcll(mk); } }
    if (cntM > CAP - 64){
      Tm = squeeze13(bM, cntM, lane);
      unsigned tb = (unsigned)(Tm >> 32);
      if (tb > mBbits){ mBbits = tb; mB = __uint_as_float(tb); }
      if (lane == 0 && tb) atomicMax(&shwM, tb);
      candM = candM && (keyM > Tm) && !((unsigned)(keyM >> 32) < mBbits);
    }
    { unsigned long long mk = __ballot(candM);
      if (mk){ int off = cntM + __popcll(mk & laneLT); if (candM) bM[off] = keyM; cntM += __popcll(mk); } }
    if (cntC > CAP - 64){
      Tc = squeeze13(bC, cntC, lane);
      unsigned cb = (unsigned)((~Tc) >> 32);
      if (cb < cbits){ cbits = cb;
        thr = 3.0f + log10f(__uint_as_float(cbits) * 1.00002f + 1e-6f); }
      if (lane == 0) atomicMin(&shwC, cb);
      candC = candC && (keyC > Tc) && !((unsigned)((~keyC) >> 32) > cbits);
    }
    { unsigned long long mk = __ballot(candC);
      if (mk){ int off = cntC + __popcll(mk & laneLT); if (candC) bC[off] = keyC; cntC += __popcll(mk); } }

    p = pn; inb = inbn; pr = prn; pb = pbn; vb = vbn; spf = spfn;
  }

  // per-wave: compact own buffers to exact top-13 at buf[0..12]
  squeeze13(bI, cntI, lane);
  squeeze13(bM, cntM, lane);
  squeeze13(bC, cntC, lane);
  __syncthreads();
  if (wv != 0) return;

  // ---- wave0: global top-13 from 4x13 survivors per criterion ----
  int w13 = lane / TK, r13 = lane - w13 * TK;       // lane -> (wave, rank)
  int kd;
  { // iou -> dynamic_k (desc-order sum, fp-exact vs ref)
    unsigned long long e = (lane < NW*TK) ? bufI[w13*CAP + r13] : 0ull;
    float ksum = 0.0f;
    for (int r = 0; r < TK; ++r){
      unsigned long long m = e; int l = lane;
      bfly_max_u64(m, l);
      ksum += __uint_as_float((unsigned)(m >> 32));
      if (lane == l) e = 0ull;
    }
    kd = (int)ksum; if (kd < 1) kd = 1;
  }
  { // metric -> fg marks
    unsigned long long e = (lane < NW*TK) ? bufM[w13*CAP + r13] : 0ull;
    for (int r = 0; r < TK; ++r){
      unsigned long long m = e; int l = lane;
      bfly_max_u64(m, l);
      if (lane == 0 && m != 0ull){
        unsigned ix = ~(unsigned)(m & 0xFFFFFFFFull);
        if (ix & 1u) atomicOr(&acc[bP + (ix >> 1)], 2u);
      }
      if (lane == l) e = 0ull;
    }
  }
  { // cost -> first kd selections; multi-detect on 1->2 transition
    unsigned long long e = (lane < NW*TK) ? bufC[w13*CAP + r13] : 0ull;
    for (int r = 0; r < kd; ++r){
      unsigned long long m = e; int l = lane;
      bfly_max_u64(m, l);
      if (lane == 0 && m != 0ull){
        unsigned pp = (unsigned)((~m) & 0xFFFFFFFFull);
        unsigned old = atomicAdd(&acc[bP + pp], (1u << 17) | ((unsigned)g << 2));
        if ((old >> 17) == 1u){
          unsigned mi = atomicAdd(mcnt, 1u);
          if (mi < MCAP) mlist[mi] = (unsigned)(bP + pp);
        }
      }
      if (lane == l) e = 0ull;
    }
  }
}

// Kernel C: uniform decode; multi priors get a placeholder (k_multi overwrites).
__global__ __launch_bounds__(256) void k_final(
    const float4* __restrict__ pred_bboxes, const int* __restrict__ gt_labels,
    const float4* __restrict__ gtb, const unsigned int* __restrict__ acc,
    float* __restrict__ out, int B, int P, int G)
{
  int b = blockIdx.y;
  int p = blockIdx.x * 256 + threadIdx.x;
  __shared__ float4 sg[MAXG];
  __shared__ int sl[MAXG];
  for (int i = threadIdx.x; i < G; i += 256){
    sg[i] = gtb[b*G + i]; sl[i] = gt_labels[b*G + i];
  }
  __syncthreads();
  if (p >= P) return;
  size_t o = (size_t)b * P + p;
  unsigned int w = acc[o];
  int cnt = (int)(w >> 17);
  bool fg = cnt > 0;
  int mg = (cnt == 1) ? (int)((w >> 2) & 0x7FFFu) : 0;  // cnt>1 -> placeholder
  float4 pb = pred_bboxes[o];
  size_t BP = (size_t)B * P;
  out[o] = fg ? (float)sl[mg] : 80.0f;
  out[BP + o] = 1.0f;
  float4 ob = fg ? sg[mg] : make_float4(0.f, 0.f, 0.f, 0.f);
  ((float4*)(out + 2*BP))[o] = ob;
  out[6*BP + o] = fg ? iou_fn(pb, sg[mg]) : 0.0f;
  out[7*BP + o] = ((w >> 1) & 1u) ? 1.0f : 0.0f;
}

// Kernel D: one wave per multi-matched prior; exact argmin cost over all g.
__global__ __launch_bounds__(256) void k_multi(
    const float4* __restrict__ pred_bboxes, const float* __restrict__ pred_scores,
    const float4* __restrict__ priors, const int* __restrict__ gt_labels,
    const float4* __restrict__ gtb, const unsigned long long* __restrict__ vmask,
    const unsigned int* __restrict__ mcnt, const unsigned int* __restrict__ mlist,
    float* __restrict__ out, int B, int P, int G, int C, int nCh)
{
  unsigned n = *mcnt; if (n > MCAP) n = MCAP;
  int lane = threadIdx.x & 63;
  int wid = (blockIdx.x * (blockDim.x >> 6)) + (threadIdx.x >> 6);
  int nw = gridDim.x * (blockDim.x >> 6);
  size_t BP = (size_t)B * P;
  for (unsigned i = wid; i < n; i += nw){
    unsigned o = mlist[i];
    int b = o / P;
    int p = o - b * P;
    float4 pb = pred_bboxes[o];
    bool vld = (vmask[(size_t)b * nCh + (p >> 6)] >> (p & 63)) & 1ull;
    int mg = 0;
    if (vld){
      float4 pr = priors[p];
      const float* srow = pred_scores + (size_t)o * C;
      unsigned long long best = 0xFFFFFFFFFFFFFFFFull;
      for (int g0 = lane; g0 < G; g0 += 64){
        float4 gbx = gtb[b*G + g0];
        float iou = iou_fn(pb, gbx);
        float s = srow[gt_labels[b*G + g0]];
        float gcx = (gbx.x + gbx.z) * 0.5f, gcy = (gbx.y + gbx.w) * 0.5f;
        float dx = pr.x - gcx, dy = pr.y - gcy;
        float dist = sqrtf(dx*dx + dy*dy) / pr.z;
        float cc = cost_full(iou, s, dist);
        unsigned long long k = ((unsigned long long)__float_as_uint(cc) << 32) | (unsigned)g0;
        if (k < best) best = k;
      }
      #pragma unroll
      for (int off = 32; off >= 1; off >>= 1){
        unsigned long long ov = __shfl_xor(best, off);
        if (ov < best) best = ov;
      }
      mg = (int)(best & 0xFFFFFFFFull);
    }
    if (lane == 0){
      float4 gbx = gtb[b*G + mg];
      out[o] = (float)gt_labels[b*G + mg];
      ((float4*)(out + 2*BP))[o] = gbx;
      out[6*BP + o] = iou_fn(pb, gbx);
    }
  }
}

extern "C" void kernel_launch(void* const* d_in, const int* in_sizes, int n_in,
                              void* d_out, int out_size, void* d_ws, size_t ws_size,
                              hipStream_t stream)
{
  const float4* pred_bboxes = (const float4*)d_in[0];
  const float*  pred_scores = (const float*)d_in[1];
  const float4* priors      = (const float4*)d_in[2];
  const int*    gt_labels   = (const int*)d_in[3];
  const float4* gt_bboxes   = (const float4*)d_in[4];
  const float*  pad         = (const float*)d_in[5];
  int P = in_sizes[2] / 4;                 // 8400
  int B = in_sizes[0] / (P * 4);           // 16
  int C = in_sizes[1] / (B * P);           // 80
  int G = in_sizes[4] / (B * 4);           // 100
  int BG = B * G;
  int nCh = (P + 63) >> 6;                 // 132

  uint8_t* ws = (uint8_t*)d_ws;
  size_t accOff  = (size_t)B * nCh * 8;                 // vmask
  size_t mcntOff = accOff + (size_t)B * P * 4;          // acc
  mcntOff = (mcntOff + 15) & ~(size_t)15;
  size_t mlistOff = mcntOff + 16;
  size_t scTOff = mlistOff + (size_t)MCAP * 4;
  scTOff = (scTOff + 15) & ~(size_t)15;
  size_t scTbytes = (size_t)B * C * P * 4;              // ~43 MB
  int useT = (scTOff + scTbytes <= ws_size);

  unsigned long long* vmask = (unsigned long long*)ws;
  unsigned int* acc   = (unsigned int*)(ws + accOff);
  unsigned int* mcnt  = (unsigned int*)(ws + mcntOff);
  unsigned int* mlist = (unsigned int*)(ws + mlistOff);
  float* scT = (float*)(ws + scTOff);
  float* out = (float*)d_out;

  dim3 gridA((P + 255) / 256, B);
  if (useT) k_tr<<<dim3(nCh, B), 256, 0, stream>>>(pred_scores, scT, P, C);
  k_valid<<<gridA, 256, 0, stream>>>(priors, gt_bboxes, pad, vmask, acc, mcnt, P, G, nCh);
  k_scan<<<BG, NW*64, 0, stream>>>(pred_bboxes, pred_scores, scT, useT,
                                   priors, gt_labels, gt_bboxes, pad, vmask,
                                   acc, mcnt, mlist, P, G, C, nCh);
  k_final<<<gridA, 256, 0, stream>>>(pred_bboxes, gt_labels, gt_bboxes, acc, out, B, P, G);
  k_multi<<<64, 256, 0, stream>>>(pred_bboxes, pred_scores, priors, gt_labels, gt_bboxes,
                                  vmask, mcnt, mlist, out, B, P, G, C, nCh);
}

// Round 10
// 275.810 us; speedup vs baseline: 1.6839x; 1.1602x over previous
//
#include <hip/hip_runtime.h>
#include <cstdint>
#include <climits>
#include <cstddef>

#define TK 13
#define MAXG 128
#define CAP 192
#define NW 4
#define MCAP 24576

__device__ __forceinline__ float iou_fn(const float4 pb, const float4 gb){
  float pa = (pb.z - pb.x) * (pb.w - pb.y);
  float ga = (gb.z - gb.x) * (gb.w - gb.y);
  float ltx = fmaxf(pb.x, gb.x), lty = fmaxf(pb.y, gb.y);
  float rbx = fminf(pb.z, gb.z), rby = fminf(pb.w, gb.w);
  float w = fmaxf(rbx - ltx, 0.0f), h = fmaxf(rby - lty, 0.0f);
  float inter = w * h;
  float uni = pa + ga - inter;
  return inter / fmaxf(uni, 1e-6f);
}

__device__ __forceinline__ float sigmoid_f(float x){ return 1.0f / (1.0f + expf(-x)); }

// Same expression order as R0-R9 (passed absmax 0) — do not alter.
__device__ __forceinline__ float cost_full(float iou, float s, float dist){
  float sig = sigmoid_f(s);
  float iouc = -logf(iou + 1e-7f) * 3.0f;
  float scale = iou - sig;
  float bce = fmaxf(s, 0.0f) + log1pf(expf(-fabsf(s))) - s * iou;
  float cls = bce * scale * scale;
  float soft = powf(10.0f, dist - 3.0f);
  return cls + iouc + soft;
}

__device__ __forceinline__ void bfly_max_u64(unsigned long long &v, int &l){
  #pragma unroll
  for (int off = 32; off >= 1; off >>= 1){
    unsigned long long ov = __shfl_xor(v, off);
    int ol = __shfl_xor(l, off);
    if (ov > v){ v = ov; l = ol; }
  }
}

// wave-level: find 13th-largest of cnt entries in buf; compact top-13 to
// buf[0..12]; return 13th key (0 if fewer than 13 nonzero). Keys unique.
__device__ __forceinline__ unsigned long long squeeze13(unsigned long long* buf, int& cnt, int lane){
  unsigned long long e0 = (lane < cnt) ? buf[lane] : 0ull;
  unsigned long long e1 = (lane + 64 < cnt) ? buf[lane + 64] : 0ull;
  unsigned long long e2 = (lane + 128 < cnt) ? buf[lane + 128] : 0ull;
  if (e0 < e2){ unsigned long long t = e0; e0 = e2; e2 = t; }
  if (e0 < e1){ unsigned long long t = e0; e0 = e1; e1 = t; }
  if (e1 < e2){ unsigned long long t = e1; e1 = e2; e2 = t; }
  unsigned long long T = 0;
  for (int r = 0; r < TK; ++r){
    unsigned long long m = e0; int l = lane;
    bfly_max_u64(m, l);
    if (lane == 0) buf[r] = m;
    T = m;
    if (lane == l){ e0 = e1; e1 = e2; e2 = 0ull; }
  }
  cnt = TK;
  return T;
}

// Kernel A: valid bitmask + acc init + multi-counter zero.
__global__ __launch_bounds__(256) void k_valid(
    const float4* __restrict__ priors, const float4* __restrict__ gtb,
    const float* __restrict__ pad, unsigned long long* __restrict__ vmask,
    unsigned int* __restrict__ acc, unsigned int* __restrict__ mcnt,
    int P, int G, int nCh)
{
  int b = blockIdx.y;
  int p = blockIdx.x * 256 + threadIdx.x;
  if (b == 0 && p == 0) *mcnt = 0u;
  __shared__ float4 sg[MAXG];
  __shared__ float sp[MAXG];
  for (int i = threadIdx.x; i < G; i += 256){ sg[i] = gtb[b*G + i]; sp[i] = pad[b*G + i]; }
  __syncthreads();
  if (p >= P) return;
  float4 pr = priors[p];
  bool v = false;
  #pragma unroll 4
  for (int g = 0; g < G; ++g){
    float4 gb = sg[g];
    bool ig = (pr.x > gb.x) && (pr.y > gb.y) && (gb.z > pr.x) && (gb.w > pr.y);
    v = v || (ig && sp[g] > 0.5f);
  }
  size_t o = (size_t)b * P + p;
  acc[o] = 0u;
  unsigned long long m = __ballot(v);
  if ((threadIdx.x & 63) == 0) vmask[(size_t)b * nCh + (p >> 6)] = m;
}

// Kernel B: one 4-wave block per (b,g). Flood-free scan: zero-metric and
// invalid-cost keys pushed only into per-wave 13-smallest-p fill pools (exact:
// index-tied keys beyond a wave's 13 smallest have >=13 better keys). Heavy
// paths (score gather, sigmoid/powf, cost_full) fire only for contenders.
__global__ __launch_bounds__(256) void k_scan(
    const float4* __restrict__ pred_bboxes, const float* __restrict__ pred_scores,
    const float4* __restrict__ priors, const int* __restrict__ gt_labels,
    const float4* __restrict__ gtbb, const float* __restrict__ pad,
    const unsigned long long* __restrict__ vmask,
    unsigned int* __restrict__ acc, unsigned int* __restrict__ mcnt,
    unsigned int* __restrict__ mlist,
    int P, int G, int C, int nCh)
{
  int bg = blockIdx.x;
  if (pad[bg] <= 0.5f) return;
  int b = bg / G;
  int g = bg - b * G;
  int tid = threadIdx.x;
  int lane = tid & 63;
  int wv = tid >> 6;
  float4 gb = gtbb[bg];
  int lbl = gt_labels[bg];
  float gcx = (gb.x + gb.z) * 0.5f, gcy = (gb.y + gb.w) * 0.5f;
  size_t bP = (size_t)b * P;
  const unsigned long long* vmb = vmask + (size_t)b * nCh;

  __shared__ unsigned long long bufM[NW*CAP], bufC[NW*CAP], bufI[NW*CAP];
  __shared__ unsigned int shwC, shwM, shwI;   // value-bits-only shared bounds
  if (tid == 0){ shwC = 0xFFFFFFFFu; shwM = 0u; shwI = 0u; }
  __syncthreads();
  unsigned long long* bM = bufM + wv*CAP;
  unsigned long long* bC = bufC + wv*CAP;
  unsigned long long* bI = bufI + wv*CAP;

  int cntM = 0, cntC = 0, cntI = 0;                 // wave-uniform
  int zM = 0, zC = 0;                               // fill-pool counts (wave-uniform)
  unsigned long long Tm = 0ull, Tc = 0ull;
  unsigned long long Ti = 0x00000000FFFFFFFFull;    // prune iou==0 from the start
  unsigned cbits = 0xFFFFFFFFu, mBbits = 0u, iBb = 0u;
  float thr = 1e30f, mB = 0.0f;
  unsigned long long laneLT = (1ull << lane) - 1ull;

  int p = wv * 64 + lane;
  bool inb = p < P;
  float4 pr = make_float4(0,0,0,0), pb = pr; bool vb = false;
  if (inb){
    pr = priors[p]; pb = pred_bboxes[bP + p]; vb = (vmb[wv] >> lane) & 1ull;
  }
  for (int c = wv; c < nCh; c += NW){
    // prefetch next chunk for this wave
    int cn = c + NW;
    int pn = cn * 64 + lane;
    bool inbn = (cn < nCh) && (pn < P);
    float4 prn = make_float4(0,0,0,0), pbn = prn; bool vbn = false;
    if (inbn){
      prn = priors[pn]; pbn = pred_bboxes[bP + pn]; vbn = (vmb[cn] >> (pn & 63)) & 1ull;
    }
    // refresh shared bounds (broadcast LDS reads; recompute thr only on change)
    { unsigned sC = shwC; if (sC < cbits){ cbits = sC;
        thr = 3.0f + log10f(__uint_as_float(cbits) * 1.00002f + 1e-6f); } }
    { unsigned sM = shwM; if (sM > mBbits){ mBbits = sM; mB = __uint_as_float(sM); } }
    { unsigned sI = shwI; if (sI > iBb) iBb = sI; }
    // ---- compute ----
    float iou = iou_fn(pb, gb);
    bool ig = inb && (pr.x > gb.x) && (pr.y > gb.y) && (gb.z > pr.x) && (gb.w > pr.y);
    bool pos = ig && (iou > 0.0f);                  // metric > 0 possible only here
    unsigned long long keyI = ((unsigned long long)__float_as_uint(iou) << 32) | (unsigned)p;
    bool candI = inb && (keyI > Ti) && !((unsigned)(keyI >> 32) < iBb);
    float i2 = iou * iou;
    float bnd = (i2 * i2) * i2 * 1.000002f;         // >= sigmoid*powf(iou,6)
    bool needm = pos && !(bnd < mB);
    float dist = 0.0f; bool needc = false;
    if (vb){
      float dx = pr.x - gcx, dy = pr.y - gcy;
      dist = sqrtf(dx*dx + dy*dy) / pr.z;
      needc = !(dist > thr);
    }
    float sc = 0.0f;
    if (needm || needc) sc = pred_scores[(bP + p) * C + lbl];
    unsigned long long keyM = 0;
    if (__ballot(needm)){
      float met = sigmoid_f(sc) * powf(iou, 6.0f);
      if (needm)
        keyM = ((unsigned long long)__float_as_uint(met) << 32)
             | (unsigned)~(unsigned)((p << 1) | 1);
    }
    if (zM < TK && inb && !pos)                     // zero-metric fill pool (13-smallest-p/wave)
      keyM = (unsigned long long)(unsigned)~(unsigned)((p << 1) | (ig ? 1 : 0));
    bool candM = (keyM != 0ull) && (keyM > Tm) && !((unsigned)(keyM >> 32) < mBbits);
    unsigned long long keyC = 0;
    if (zC < TK && inb && !vb)                      // invalid-cost fill pool
      keyC = ~(((unsigned long long)__float_as_uint(1e8f) << 32) | (unsigned)p);
    if (__ballot(needc)){
      float cst = cost_full(iou, sc, dist);
      if (needc)
        keyC = ~(((unsigned long long)__float_as_uint(cst) << 32) | (unsigned)p);
    }
    bool candC = (keyC != 0ull) && (keyC > Tc) && !((unsigned)((~keyC) >> 32) > cbits);
    // ---- pushes (squeeze-on-full; shared bound update at squeeze only) ----
    if (cntI > CAP - 64){
      Ti = squeeze13(bI, cntI, lane);
      unsigned ib = (unsigned)(Ti >> 32);
      if (ib > iBb) iBb = ib;
      if (lane == 0 && ib) atomicMax(&shwI, ib);
      candI = candI && (keyI > Ti) && !((unsigned)(keyI >> 32) < iBb);
    }
    { unsigned long long mk = __ballot(candI);
      if (mk){ int off = cntI + __popcll(mk & laneLT); if (candI) bI[off] = keyI; cntI += __popcll(mk); } }
    if (cntM > CAP - 64){
      Tm = squeeze13(bM, cntM, lane);
      unsigned tb = (unsigned)(Tm >> 32);
      if (tb > mBbits){ mBbits = tb; mB = __uint_as_float(tb); }
      if (lane == 0 && tb) atomicMax(&shwM, tb);
      candM = candM && (keyM > Tm) && !((unsigned)(keyM >> 32) < mBbits);
    }
    { unsigned long long mk = __ballot(candM);
      if (mk){
        int off = cntM + __popcll(mk & laneLT);
        if (candM) bM[off] = keyM;
        cntM += __popcll(mk);
        unsigned long long zk = __ballot(candM && !pos);
        zM += __popcll(zk);
      } }
    if (cntC > CAP - 64){
      Tc = squeeze13(bC, cntC, lane);
      unsigned cb = (unsigned)((~Tc) >> 32);
      if (cb < cbits){ cbits = cb;
        thr = 3.0f + log10f(__uint_as_float(cbits) * 1.00002f + 1e-6f); }
      if (lane == 0) atomicMin(&shwC, cb);
      candC = candC && (keyC > Tc) && !((unsigned)((~keyC) >> 32) > cbits);
    }
    { unsigned long long mk = __ballot(candC);
      if (mk){
        int off = cntC + __popcll(mk & laneLT);
        if (candC) bC[off] = keyC;
        cntC += __popcll(mk);
        unsigned long long zk = __ballot(candC && !vb);
        zC += __popcll(zk);
      } }

    p = pn; inb = inbn; pr = prn; pb = pbn; vb = vbn;
  }

  // per-wave: compact own buffers to exact top-13 at buf[0..12]
  squeeze13(bI, cntI, lane);
  squeeze13(bM, cntM, lane);
  squeeze13(bC, cntC, lane);
  __syncthreads();
  if (wv != 0) return;

  // ---- wave0: global top-13 from 4x13 survivors per criterion ----
  int w13 = lane / TK, r13 = lane - w13 * TK;       // lane -> (wave, rank)
  int kd;
  { // iou -> dynamic_k (desc-order sum, fp-exact vs ref)
    unsigned long long e = (lane < NW*TK) ? bufI[w13*CAP + r13] : 0ull;
    float ksum = 0.0f;
    for (int r = 0; r < TK; ++r){
      unsigned long long m = e; int l = lane;
      bfly_max_u64(m, l);
      ksum += __uint_as_float((unsigned)(m >> 32));
      if (lane == l) e = 0ull;
    }
    kd = (int)ksum; if (kd < 1) kd = 1;
  }
  { // metric -> fg marks
    unsigned long long e = (lane < NW*TK) ? bufM[w13*CAP + r13] : 0ull;
    for (int r = 0; r < TK; ++r){
      unsigned long long m = e; int l = lane;
      bfly_max_u64(m, l);
      if (lane == 0 && m != 0ull){
        unsigned ix = ~(unsigned)(m & 0xFFFFFFFFull);
        if (ix & 1u) atomicOr(&acc[bP + (ix >> 1)], 2u);
      }
      if (lane == l) e = 0ull;
    }
  }
  { // cost -> first kd selections; multi-detect on 1->2 transition
    unsigned long long e = (lane < NW*TK) ? bufC[w13*CAP + r13] : 0ull;
    for (int r = 0; r < kd; ++r){
      unsigned long long m = e; int l = lane;
      bfly_max_u64(m, l);
      if (lane == 0 && m != 0ull){
        unsigned pp = (unsigned)((~m) & 0xFFFFFFFFull);
        unsigned old = atomicAdd(&acc[bP + pp], (1u << 17) | ((unsigned)g << 2));
        if ((old >> 17) == 1u){
          unsigned mi = atomicAdd(mcnt, 1u);
          if (mi < MCAP) mlist[mi] = (unsigned)(bP + pp);
        }
      }
      if (lane == l) e = 0ull;
    }
  }
}

// Kernel C: uniform decode; multi priors get a placeholder (k_multi overwrites).
__global__ __launch_bounds__(256) void k_final(
    const float4* __restrict__ pred_bboxes, const int* __restrict__ gt_labels,
    const float4* __restrict__ gtb, const unsigned int* __restrict__ acc,
    float* __restrict__ out, int B, int P, int G)
{
  int b = blockIdx.y;
  int p = blockIdx.x * 256 + threadIdx.x;
  __shared__ float4 sg[MAXG];
  __shared__ int sl[MAXG];
  for (int i = threadIdx.x; i < G; i += 256){
    sg[i] = gtb[b*G + i]; sl[i] = gt_labels[b*G + i];
  }
  __syncthreads();
  if (p >= P) return;
  size_t o = (size_t)b * P + p;
  unsigned int w = acc[o];
  int cnt = (int)(w >> 17);
  bool fg = cnt > 0;
  int mg = (cnt == 1) ? (int)((w >> 2) & 0x7FFFu) : 0;  // cnt>1 -> placeholder
  float4 pb = pred_bboxes[o];
  size_t BP = (size_t)B * P;
  out[o] = fg ? (float)sl[mg] : 80.0f;
  out[BP + o] = 1.0f;
  float4 ob = fg ? sg[mg] : make_float4(0.f, 0.f, 0.f, 0.f);
  ((float4*)(out + 2*BP))[o] = ob;
  out[6*BP + o] = fg ? iou_fn(pb, sg[mg]) : 0.0f;
  out[7*BP + o] = ((w >> 1) & 1u) ? 1.0f : 0.0f;
}

// Kernel D: one wave per multi-matched prior; exact argmin cost over all g.
__global__ __launch_bounds__(256) void k_multi(
    const float4* __restrict__ pred_bboxes, const float* __restrict__ pred_scores,
    const float4* __restrict__ priors, const int* __restrict__ gt_labels,
    const float4* __restrict__ gtb, const unsigned long long* __restrict__ vmask,
    const unsigned int* __restrict__ mcnt, const unsigned int* __restrict__ mlist,
    float* __restrict__ out, int B, int P, int G, int C, int nCh)
{
  unsigned n = *mcnt; if (n > MCAP) n = MCAP;
  int lane = threadIdx.x & 63;
  int wid = (blockIdx.x * (blockDim.x >> 6)) + (threadIdx.x >> 6);
  int nw = gridDim.x * (blockDim.x >> 6);
  size_t BP = (size_t)B * P;
  for (unsigned i = wid; i < n; i += nw){
    unsigned o = mlist[i];
    int b = o / P;
    int p = o - b * P;
    float4 pb = pred_bboxes[o];
    bool vld = (vmask[(size_t)b * nCh + (p >> 6)] >> (p & 63)) & 1ull;
    int mg = 0;
    if (vld){
      float4 pr = priors[p];
      const float* srow = pred_scores + (size_t)o * C;
      unsigned long long best = 0xFFFFFFFFFFFFFFFFull;
      for (int g0 = lane; g0 < G; g0 += 64){
        float4 gbx = gtb[b*G + g0];
        float iou = iou_fn(pb, gbx);
        float s = srow[gt_labels[b*G + g0]];
        float gcx = (gbx.x + gbx.z) * 0.5f, gcy = (gbx.y + gbx.w) * 0.5f;
        float dx = pr.x - gcx, dy = pr.y - gcy;
        float dist = sqrtf(dx*dx + dy*dy) / pr.z;
        float cc = cost_full(iou, s, dist);
        unsigned long long k = ((unsigned long long)__float_as_uint(cc) << 32) | (unsigned)g0;
        if (k < best) best = k;
      }
      #pragma unroll
      for (int off = 32; off >= 1; off >>= 1){
        unsigned long long ov = __shfl_xor(best, off);
        if (ov < best) best = ov;
      }
      mg = (int)(best & 0xFFFFFFFFull);
    }
    if (lane == 0){
      float4 gbx = gtb[b*G + mg];
      out[o] = (float)gt_labels[b*G + mg];
      ((float4*)(out + 2*BP))[o] = gbx;
      out[6*BP + o] = iou_fn(pb, gbx);
    }
  }
}

extern "C" void kernel_launch(void* const* d_in, const int* in_sizes, int n_in,
                              void* d_out, int out_size, void* d_ws, size_t ws_size,
                              hipStream_t stream)
{
  const float4* pred_bboxes = (const float4*)d_in[0];
  const float*  pred_scores = (const float*)d_in[1];
  const float4* priors      = (const float4*)d_in[2];
  const int*    gt_labels   = (const int*)d_in[3];
  const float4* gt_bboxes   = (const float4*)d_in[4];
  const float*  pad         = (const float*)d_in[5];
  int P = in_sizes[2] / 4;                 // 8400
  int B = in_sizes[0] / (P * 4);           // 16
  int C = in_sizes[1] / (B * P);           // 80
  int G = in_sizes[4] / (B * 4);           // 100
  int BG = B * G;
  int nCh = (P + 63) >> 6;                 // 132

  uint8_t* ws = (uint8_t*)d_ws;
  size_t accOff  = (size_t)B * nCh * 8;                 // vmask
  size_t mcntOff = accOff + (size_t)B * P * 4;          // acc
  mcntOff = (mcntOff + 15) & ~(size_t)15;
  size_t mlistOff = mcntOff + 16;

  unsigned long long* vmask = (unsigned long long*)ws;
  unsigned int* acc   = (unsigned int*)(ws + accOff);
  unsigned int* mcnt  = (unsigned int*)(ws + mcntOff);
  unsigned int* mlist = (unsigned int*)(ws + mlistOff);
  float* out = (float*)d_out;

  dim3 gridA((P + 255) / 256, B);
  k_valid<<<gridA, 256, 0, stream>>>(priors, gt_bboxes, pad, vmask, acc, mcnt, P, G, nCh);
  k_scan<<<BG, NW*64, 0, stream>>>(pred_bboxes, pred_scores,
                                   priors, gt_labels, gt_bboxes, pad, vmask,
                                   acc, mcnt, mlist, P, G, C, nCh);
  k_final<<<gridA, 256, 0, stream>>>(pred_bboxes, gt_labels, gt_bboxes, acc, out, B, P, G);
  k_multi<<<64, 256, 0, stream>>>(pred_bboxes, pred_scores, priors, gt_labels, gt_bboxes,
                                  vmask, mcnt, mlist, out, B, P, G, C, nCh);
}